// Round 1
// baseline (177.063 us; speedup 1.0000x reference)
//
#include <hip/hip_runtime.h>
#include <hip/hip_bf16.h>

#define B_ 8
#define T_ 12
#define N_ 2048
#define C_ 64

#define BM 128
#define BK 64
#define LDM 72    // padded LDS row stride (bf16 elems) for As/Bs
#define LDE 136   // padded LDS row stride for E / Wt

typedef __attribute__((ext_vector_type(4))) float f32x4;
typedef __attribute__((ext_vector_type(4))) __bf16 bf16x4;
typedef __attribute__((ext_vector_type(8))) __bf16 bf16x8;

// ---------------- lambda MLP: c1[t], c2[t] ----------------
__global__ void lam_kernel(const float* __restrict__ st, const float* __restrict__ W1,
                           const float* __restrict__ b1, const float* __restrict__ W2,
                           const float* __restrict__ b2, float* __restrict__ cbuf) {
    const int t = threadIdx.x >> 5;   // 0..11  (384 threads = 12 groups of 32)
    const int h = threadIdx.x & 31;
    if (t >= T_) return;
    float acc = b1[h];
    #pragma unroll 8
    for (int e = 0; e < 64; ++e) acc += st[t * 64 + e] * W1[e * 32 + h];
    float hv = fmaxf(acc, 0.f) * W2[h];
    #pragma unroll
    for (int off = 16; off; off >>= 1) hv += __shfl_down(hv, off, 32);
    if (h == 0) {
        float lam = 1.f + fmaxf(hv + b2[0], 0.f);
        cbuf[t]      = 2.f - 2.f / lam;   // c1
        cbuf[T_ + t] = 2.f / lam;         // c2
    }
}

// ---------------- fused main kernel ----------------
// out[bt, n, o] = c1*  (x[bt] @ W0)[n,o] + c2 * ((adj @ x[bt]) @ W1)[n,o] + bias[o]
__global__ __launch_bounds__(256, 3) void dgcn_main(
    const float* __restrict__ x, const float* __restrict__ adj,
    const float* __restrict__ weights, const float* __restrict__ bias,
    const float* __restrict__ cbuf, float* __restrict__ out)
{
    // union: main-loop tiles (As[128][72] + Bs[64][72] = 13824) vs epilogue E[128][136] = 17408
    __shared__ __align__(16) __bf16 smem[BM * LDE];
    __shared__ __align__(16) __bf16 Wt[64 * LDE];   // Wt[o][k] : k<64 -> W1[k][o], k>=64 -> W0[k-64][o]
    __bf16* As = smem;              // [BM][LDM]   adj tile (row-major, k contiguous)
    __bf16* Bs = smem + BM * LDM;   // [64][LDM]   x tile TRANSPOSED: Bs[c][k]
    __bf16* E  = smem;              // [BM][LDE]   epilogue concat tile

    const int mtile = blockIdx.x;          // 0..15
    const int bt    = blockIdx.y;          // 0..95
    const int tloc  = bt % T_;
    const int m0    = mtile * BM;
    const int tid   = threadIdx.x;
    const int lane  = tid & 63;
    const int w     = tid >> 6;            // wave 0..3

    const float c1 = cbuf[tloc];
    const float c2 = cbuf[T_ + tloc];
    const float* xbt = x + (size_t)bt * N_ * C_;

    // stage Wt once (region disjoint from As/Bs)
    for (int e = tid; e < 2 * 64 * 64; e += 256) {
        int kk = e >> 6, o = e & 63;
        float v = (kk < 64) ? weights[4096 + kk * 64 + o]      // W1 (adj support)
                            : weights[(kk - 64) * 64 + o];     // W0 (identity support)
        Wt[o * LDE + kk] = (__bf16)v;
    }

    f32x4 acc[2][4] = {};
    const int c4 = tid & 15;      // float4 column group
    const int rg = tid >> 4;      // 0..15
    const int lr = lane & 15;
    const int lk = lane >> 4;

    for (int kt = 0; kt < N_ / BK; ++kt) {
        const int k0 = kt * BK;
        __syncthreads();   // protect previous iteration's frag reads
        // ---- stage As: adj[m0+r][k0 + 4*c4 .. +3], r = rg + 16j ----
        #pragma unroll
        for (int j = 0; j < 8; ++j) {
            const int r = rg + 16 * j;
            const float4 f = *(const float4*)&adj[(size_t)(m0 + r) * N_ + k0 + 4 * c4];
            bf16x4 h = { (__bf16)f.x, (__bf16)f.y, (__bf16)f.z, (__bf16)f.w };
            *(bf16x4*)&As[r * LDM + 4 * c4] = h;
        }
        // ---- stage Bs transposed: Bs[c][k] = x[k0+k][c] ----
        #pragma unroll
        for (int j = 0; j < 4; ++j) {
            const int k  = (tid & 15) + 16 * j;
            const int c0 = 4 * (tid >> 4);
            const float4 f = *(const float4*)&xbt[(size_t)(k0 + k) * C_ + c0];
            Bs[(c0 + 0) * LDM + k] = (__bf16)f.x;
            Bs[(c0 + 1) * LDM + k] = (__bf16)f.y;
            Bs[(c0 + 2) * LDM + k] = (__bf16)f.z;
            Bs[(c0 + 3) * LDM + k] = (__bf16)f.w;
        }
        __syncthreads();
        // ---- MFMA: wave w owns rows w*32..w*32+31, all 64 cols ----
        #pragma unroll
        for (int ks = 0; ks < 2; ++ks) {
            bf16x8 a0 = *(const bf16x8*)&As[(w * 32 +  0 + lr) * LDM + ks * 32 + lk * 8];
            bf16x8 a1 = *(const bf16x8*)&As[(w * 32 + 16 + lr) * LDM + ks * 32 + lk * 8];
            #pragma unroll
            for (int nj = 0; nj < 4; ++nj) {
                bf16x8 b = *(const bf16x8*)&Bs[(nj * 16 + lr) * LDM + ks * 32 + lk * 8];
                acc[0][nj] = __builtin_amdgcn_mfma_f32_16x16x32_bf16(a0, b, acc[0][nj], 0, 0, 0);
                acc[1][nj] = __builtin_amdgcn_mfma_f32_16x16x32_bf16(a1, b, acc[1][nj], 0, 0, 0);
            }
        }
    }
    __syncthreads();  // As/Bs dead; build E

    // ---- E cols 64..127 : c1 * x[m0+r][i] ----
    #pragma unroll
    for (int j = 0; j < 8; ++j) {
        const int r = rg + 16 * j;
        const float4 f = *(const float4*)&xbt[(size_t)(m0 + r) * C_ + 4 * c4];
        bf16x4 h = { (__bf16)(c1 * f.x), (__bf16)(c1 * f.y), (__bf16)(c1 * f.z), (__bf16)(c1 * f.w) };
        *(bf16x4*)&E[r * LDE + 64 + 4 * c4] = h;
    }
    // ---- E cols 0..63 : c2 * (adj@x) from accumulators ----
    #pragma unroll
    for (int mi = 0; mi < 2; ++mi)
        #pragma unroll
        for (int nj = 0; nj < 4; ++nj)
            #pragma unroll
            for (int q = 0; q < 4; ++q) {
                const int row = w * 32 + mi * 16 + lk * 4 + q;
                const int col = nj * 16 + lr;
                E[row * LDE + col] = (__bf16)(c2 * acc[mi][nj][q]);
            }
    __syncthreads();

    // ---- epilogue GEMM: out_tile = E[128x128] @ Wcat (K=128) ----
    f32x4 oacc[2][4] = {};
    #pragma unroll
    for (int ks = 0; ks < 4; ++ks) {
        bf16x8 a0 = *(const bf16x8*)&E[(w * 32 +  0 + lr) * LDE + ks * 32 + lk * 8];
        bf16x8 a1 = *(const bf16x8*)&E[(w * 32 + 16 + lr) * LDE + ks * 32 + lk * 8];
        #pragma unroll
        for (int nj = 0; nj < 4; ++nj) {
            bf16x8 bw = *(const bf16x8*)&Wt[(nj * 16 + lr) * LDE + ks * 32 + lk * 8];
            oacc[0][nj] = __builtin_amdgcn_mfma_f32_16x16x32_bf16(a0, bw, oacc[0][nj], 0, 0, 0);
            oacc[1][nj] = __builtin_amdgcn_mfma_f32_16x16x32_bf16(a1, bw, oacc[1][nj], 0, 0, 0);
        }
    }
    // ---- bias + store ----
    float* obt = out + (size_t)bt * N_ * C_;
    #pragma unroll
    for (int nj = 0; nj < 4; ++nj) {
        const float bv = bias[nj * 16 + lr];
        #pragma unroll
        for (int mi = 0; mi < 2; ++mi)
            #pragma unroll
            for (int q = 0; q < 4; ++q) {
                const int row = w * 32 + mi * 16 + lk * 4 + q;
                obt[(size_t)(m0 + row) * C_ + nj * 16 + lr] = oacc[mi][nj][q] + bv;
            }
    }
}

extern "C" void kernel_launch(void* const* d_in, const int* in_sizes, int n_in,
                              void* d_out, int out_size, void* d_ws, size_t ws_size,
                              hipStream_t stream) {
    const float* x       = (const float*)d_in[0];
    const float* adj     = (const float*)d_in[1];
    const float* st_emb  = (const float*)d_in[2];
    const float* weights = (const float*)d_in[3];
    const float* bias    = (const float*)d_in[4];
    const float* W1      = (const float*)d_in[5];
    const float* b1      = (const float*)d_in[6];
    const float* W2      = (const float*)d_in[7];
    const float* b2      = (const float*)d_in[8];
    float* out  = (float*)d_out;
    float* cbuf = (float*)d_ws;   // 24 floats: c1[12], c2[12]

    lam_kernel<<<1, 384, 0, stream>>>(st_emb, W1, b1, W2, b2, cbuf);
    dgcn_main<<<dim3(N_ / BM, B_ * T_), 256, 0, stream>>>(x, adj, weights, bias, cbuf, out);
}

// Round 3
// 90.052 us; speedup vs baseline: 1.9662x; 1.9662x over previous
//
#include <hip/hip_runtime.h>
#include <hip/hip_bf16.h>

#define B_ 8
#define T_ 12
#define N_ 2048
#define C_ 64
#define BM 128
#define BK 64

typedef __attribute__((ext_vector_type(4))) float f32x4;
typedef __attribute__((ext_vector_type(4))) __bf16 bf16x4;
typedef __attribute__((ext_vector_type(8))) __bf16 bf16x8;

#define GAS __attribute__((address_space(1)))
#define LAS __attribute__((address_space(3)))

static __device__ __forceinline__ void gld_lds16(const void* g, void* l) {
    __builtin_amdgcn_global_load_lds((const GAS void*)g, (LAS void*)l, 16, 0, 0);
}

// ws layout (bytes)
#define WS_CBUF 0
#define WS_WTB  1024
#define WS_ADJB 32768
#define WS_XT   (32768 + 8388608)
#define WS_NEED ((size_t)(WS_XT) + 25165824)

// ---------------- lambda MLP (fallback path) ----------------
__global__ void lam_kernel(const float* __restrict__ st, const float* __restrict__ W1,
                           const float* __restrict__ b1, const float* __restrict__ W2,
                           const float* __restrict__ b2, float* __restrict__ cbuf) {
    const int t = threadIdx.x >> 5;
    const int h = threadIdx.x & 31;
    if (t >= T_) return;
    float acc = b1[h];
    #pragma unroll 8
    for (int e = 0; e < 64; ++e) acc += st[t * 64 + e] * W1[e * 32 + h];
    float hv = fmaxf(acc, 0.f) * W2[h];
    #pragma unroll
    for (int off = 16; off; off >>= 1) hv += __shfl_down(hv, off, 32);
    if (h == 0) {
        float lam = 1.f + fmaxf(hv + b2[0], 0.f);
        cbuf[t]      = 2.f - 2.f / lam;
        cbuf[T_ + t] = 2.f / lam;
    }
}

// ---------------- lambda MLP + Wcat->bf16 (fast path) ----------------
__global__ void lamw_kernel(const float* __restrict__ st, const float* __restrict__ W1,
                            const float* __restrict__ b1, const float* __restrict__ W2,
                            const float* __restrict__ b2, const float* __restrict__ weights,
                            float* __restrict__ cbuf, __bf16* __restrict__ WtB) {
    const int t = threadIdx.x >> 5;
    const int h = threadIdx.x & 31;
    if (t < T_) {
        float acc = b1[h];
        #pragma unroll 8
        for (int e = 0; e < 64; ++e) acc += st[t * 64 + e] * W1[e * 32 + h];
        float hv = fmaxf(acc, 0.f) * W2[h];
        #pragma unroll
        for (int off = 16; off; off >>= 1) hv += __shfl_down(hv, off, 32);
        if (h == 0) {
            float lam = 1.f + fmaxf(hv + b2[0], 0.f);
            cbuf[t]      = 2.f - 2.f / lam;
            cbuf[T_ + t] = 2.f / lam;
        }
    }
    // WtB[o][k]: k<64 -> W1supp = weights[1][k][o] ; k>=64 -> W0 = weights[0][k-64][o]
    for (int e = threadIdx.x; e < 64 * 128; e += 512) {
        int o = e >> 7, k = e & 127;
        float v = (k < 64) ? weights[4096 + k * 64 + o] : weights[(k - 64) * 64 + o];
        WtB[o * 128 + k] = (__bf16)v;
    }
}

// ---------------- adj fp32 -> bf16 ----------------
__global__ void cvt_adj(const float* __restrict__ adj, __bf16* __restrict__ adjb) {
    const int i = (blockIdx.x * 256 + threadIdx.x) * 8;
    const float4 f0 = *(const float4*)&adj[i];
    const float4 f1 = *(const float4*)&adj[i + 4];
    bf16x8 h = { (__bf16)f0.x, (__bf16)f0.y, (__bf16)f0.z, (__bf16)f0.w,
                 (__bf16)f1.x, (__bf16)f1.y, (__bf16)f1.z, (__bf16)f1.w };
    *(bf16x8*)&adjb[i] = h;
}

// ---------------- x fp32 [bt][n][c] -> bf16 xT [bt][c][n] ----------------
__global__ void cvt_x(const float* __restrict__ x, __bf16* __restrict__ xT) {
    __shared__ __align__(16) __bf16 t[64][72];
    const int bt = blockIdx.y, n0 = blockIdx.x * 64;
    const int tid = threadIdx.x;
    {
        const int r = tid >> 2, c0 = (tid & 3) * 16;
        const float* src = x + ((size_t)bt * N_ + n0 + r) * C_ + c0;
        #pragma unroll
        for (int i = 0; i < 4; ++i) {
            float4 f = *(const float4*)(src + 4 * i);
            t[c0 + 4 * i + 0][r] = (__bf16)f.x;
            t[c0 + 4 * i + 1][r] = (__bf16)f.y;
            t[c0 + 4 * i + 2][r] = (__bf16)f.z;
            t[c0 + 4 * i + 3][r] = (__bf16)f.w;
        }
    }
    __syncthreads();
    {
        const int c = tid >> 2, nf = (tid & 3) * 16;
        __bf16* dst = xT + ((size_t)bt * C_ + c) * N_ + n0 + nf;
        *(bf16x8*)(dst)     = *(const bf16x8*)&t[c][nf];
        *(bf16x8*)(dst + 8) = *(const bf16x8*)&t[c][nf + 8];
    }
}

// ---------------- fast main kernel ----------------
// LDS: As [0,16384) rows 128B swz; Bs [16384,32768) 2bt x 64 c-rows swz;
//      Wt [32768,49152) 64 o-rows 256B swz; epilogue E [0,32768) 128 rows 256B swz.
__global__ __launch_bounds__(256, 3) void dgcn_main2(
    const __bf16* __restrict__ adjb, const __bf16* __restrict__ xT,
    const float* __restrict__ x, const __bf16* __restrict__ WtB,
    const float* __restrict__ bias, const float* __restrict__ cbuf,
    float* __restrict__ out)
{
    __shared__ __align__(16) __bf16 smem[24576];   // 49152 B
    char* sb = (char*)smem;

    const int m0  = blockIdx.x * BM;
    const int btg = blockIdx.y;                    // 0..47 (2 bt each)
    const int tid = threadIdx.x;
    const int l   = tid & 63, w = tid >> 6;
    const int wr  = w >> 1, wc = w & 1;
    const int lr  = l & 15, lk = l >> 4;           // lk in 0..3

    // --- stage Wt once (region untouched by main loop) ---
    // Wt rows are 256 B = SIXTEEN 16B slots: o = s>>4, j = s&15  (round-2 bug was s>>3/s&7)
    #pragma unroll
    for (int i = 0; i < 4; ++i) {
        int s = (w * 4 + i) * 64 + l;              // 0..1023
        int o = s >> 4, j = s & 15;
        *(bf16x8*)(sb + 32768 + s * 16) = *(const bf16x8*)(WtB + o * 128 + 8 * (j ^ (o & 7)));
    }

    // --- per-lane inverse-swizzled global sources for global_load_lds ---
    const __bf16* srcA[4];
    const __bf16* srcB[4];
    #pragma unroll
    for (int i = 0; i < 4; ++i) {
        int s = (w * 4 + i) * 64 + l;              // 0..1023
        int r = s >> 3, j = s & 7;                 // As rows are 128 B = 8 slots
        srcA[i] = adjb + (size_t)(m0 + r) * N_ + 8 * (j ^ (r & 7));
        int bb = s >> 9, c = (s >> 3) & 63;
        srcB[i] = xT + ((size_t)(btg * 2 + bb) * C_ + c) * N_ + 8 * (j ^ (c & 7));
    }

    f32x4 acc[4][4] = {};

    for (int kt = 0; kt < N_ / BK; ++kt) {
        __syncthreads();                           // prev frags consumed
        #pragma unroll
        for (int i = 0; i < 4; ++i) {
            gld_lds16(srcA[i], sb + (w * 4 + i) * 1024);
            gld_lds16(srcB[i], sb + 16384 + (w * 4 + i) * 1024);
            srcA[i] += BK;
            srcB[i] += BK;
        }
        __syncthreads();                           // vmcnt(0) drain before barrier
        #pragma unroll
        for (int ks = 0; ks < 2; ++ks) {
            const int kb = ks * 64 + lk * 16;
            bf16x8 a[4];
            #pragma unroll
            for (int mi = 0; mi < 4; ++mi) {
                int rr = wr * 64 + mi * 16 + lr;
                a[mi] = *(const bf16x8*)(sb + rr * 128 + (kb ^ ((rr & 7) << 4)));
            }
            #pragma unroll
            for (int nj = 0; nj < 4; ++nj) {
                int cc = nj * 16 + lr;
                bf16x8 b = *(const bf16x8*)(sb + 16384 + wc * 8192 + cc * 128 + (kb ^ ((cc & 7) << 4)));
                #pragma unroll
                for (int mi = 0; mi < 4; ++mi)
                    acc[mi][nj] = __builtin_amdgcn_mfma_f32_16x16x32_bf16(a[mi], b, acc[mi][nj], 0, 0, 0);
            }
        }
    }

    // ---------------- epilogue: per bt, E = [c2*Y | c1*x], out = E @ Wt + bias ----------------
    #pragma unroll
    for (int bb = 0; bb < 2; ++bb) {
        const int btA = btg * 2 + bb;
        const int tloc = btA % T_;
        const float c1 = cbuf[tloc];
        const float c2 = cbuf[T_ + tloc];
        __syncthreads();                           // E region free
        if (wc == bb) {                            // Y part (cols 0..63)
            #pragma unroll
            for (int mi = 0; mi < 4; ++mi)
                #pragma unroll
                for (int nj = 0; nj < 4; ++nj)
                    #pragma unroll
                    for (int q = 0; q < 4; ++q) {
                        int row = wr * 64 + mi * 16 + lk * 4 + q;
                        int colb = (nj * 16 + lr) * 2;
                        *(__bf16*)(sb + row * 256 + (colb ^ ((row & 7) << 4))) =
                            (__bf16)(c2 * acc[mi][nj][q]);
                    }
        }
        {                                          // identity part (cols 64..127)
            int row = w * 32 + (l >> 1);
            int c0 = (l & 1) * 32;
            const float* xs = x + ((size_t)btA * N_ + m0 + row) * C_ + c0;
            #pragma unroll
            for (int i = 0; i < 4; ++i) {
                float4 f0 = *(const float4*)(xs + 8 * i);
                float4 f1 = *(const float4*)(xs + 8 * i + 4);
                bf16x8 h = { (__bf16)(c1 * f0.x), (__bf16)(c1 * f0.y),
                             (__bf16)(c1 * f0.z), (__bf16)(c1 * f0.w),
                             (__bf16)(c1 * f1.x), (__bf16)(c1 * f1.y),
                             (__bf16)(c1 * f1.z), (__bf16)(c1 * f1.w) };
                int colb = 128 + c0 * 2 + 16 * i;
                *(bf16x8*)(sb + row * 256 + (colb ^ ((row & 7) << 4))) = h;
            }
        }
        __syncthreads();
        f32x4 oacc[2][4] = {};
        #pragma unroll
        for (int ks = 0; ks < 4; ++ks) {
            const int kb = ks * 64 + lk * 16;
            bf16x8 ea[2];
            #pragma unroll
            for (int mi2 = 0; mi2 < 2; ++mi2) {
                int row = w * 32 + mi2 * 16 + lr;
                ea[mi2] = *(const bf16x8*)(sb + row * 256 + (kb ^ ((row & 7) << 4)));
            }
            #pragma unroll
            for (int nj = 0; nj < 4; ++nj) {
                int o = nj * 16 + lr;
                bf16x8 bw = *(const bf16x8*)(sb + 32768 + o * 256 + (kb ^ ((o & 7) << 4)));
                oacc[0][nj] = __builtin_amdgcn_mfma_f32_16x16x32_bf16(ea[0], bw, oacc[0][nj], 0, 0, 0);
                oacc[1][nj] = __builtin_amdgcn_mfma_f32_16x16x32_bf16(ea[1], bw, oacc[1][nj], 0, 0, 0);
            }
        }
        float* ob = out + (size_t)btA * N_ * C_;
        #pragma unroll
        for (int nj = 0; nj < 4; ++nj) {
            const float bv = bias[nj * 16 + lr];
            #pragma unroll
            for (int mi2 = 0; mi2 < 2; ++mi2)
                #pragma unroll
                for (int q = 0; q < 4; ++q) {
                    int row = w * 32 + mi2 * 16 + lk * 4 + q;
                    ob[(size_t)(m0 + row) * C_ + nj * 16 + lr] = oacc[mi2][nj][q] + bv;
                }
        }
    }
}

// ---------------- fallback (round-1 verified) ----------------
#define LDM 72
#define LDE 136
__global__ __launch_bounds__(256, 3) void dgcn_fb(
    const float* __restrict__ x, const float* __restrict__ adj,
    const float* __restrict__ weights, const float* __restrict__ bias,
    const float* __restrict__ cbuf, float* __restrict__ out)
{
    __shared__ __align__(16) __bf16 smem[BM * LDE];
    __shared__ __align__(16) __bf16 Wt[64 * LDE];
    __bf16* As = smem;
    __bf16* Bs = smem + BM * LDM;
    __bf16* E  = smem;

    const int mtile = blockIdx.x;
    const int bt    = blockIdx.y;
    const int tloc  = bt % T_;
    const int m0    = mtile * BM;
    const int tid   = threadIdx.x;
    const int lane  = tid & 63;
    const int w     = tid >> 6;

    const float c1 = cbuf[tloc];
    const float c2 = cbuf[T_ + tloc];
    const float* xbt = x + (size_t)bt * N_ * C_;

    for (int e = tid; e < 2 * 64 * 64; e += 256) {
        int kk = e >> 6, o = e & 63;
        float v = (kk < 64) ? weights[4096 + kk * 64 + o] : weights[(kk - 64) * 64 + o];
        Wt[o * LDE + kk] = (__bf16)v;
    }

    f32x4 acc[2][4] = {};
    const int c4 = tid & 15;
    const int rg = tid >> 4;
    const int lr = lane & 15;
    const int lk = lane >> 4;

    for (int kt = 0; kt < N_ / BK; ++kt) {
        const int k0 = kt * BK;
        __syncthreads();
        #pragma unroll
        for (int j = 0; j < 8; ++j) {
            const int r = rg + 16 * j;
            const float4 f = *(const float4*)&adj[(size_t)(m0 + r) * N_ + k0 + 4 * c4];
            bf16x4 h = { (__bf16)f.x, (__bf16)f.y, (__bf16)f.z, (__bf16)f.w };
            *(bf16x4*)&As[r * LDM + 4 * c4] = h;
        }
        #pragma unroll
        for (int j = 0; j < 4; ++j) {
            const int k  = (tid & 15) + 16 * j;
            const int c0 = 4 * (tid >> 4);
            const float4 f = *(const float4*)&xbt[(size_t)(k0 + k) * C_ + c0];
            Bs[(c0 + 0) * LDM + k] = (__bf16)f.x;
            Bs[(c0 + 1) * LDM + k] = (__bf16)f.y;
            Bs[(c0 + 2) * LDM + k] = (__bf16)f.z;
            Bs[(c0 + 3) * LDM + k] = (__bf16)f.w;
        }
        __syncthreads();
        #pragma unroll
        for (int ks = 0; ks < 2; ++ks) {
            bf16x8 a0 = *(const bf16x8*)&As[(w * 32 +  0 + lr) * LDM + ks * 32 + lk * 8];
            bf16x8 a1 = *(const bf16x8*)&As[(w * 32 + 16 + lr) * LDM + ks * 32 + lk * 8];
            #pragma unroll
            for (int nj = 0; nj < 4; ++nj) {
                bf16x8 b = *(const bf16x8*)&Bs[(nj * 16 + lr) * LDM + ks * 32 + lk * 8];
                acc[0][nj] = __builtin_amdgcn_mfma_f32_16x16x32_bf16(a0, b, acc[0][nj], 0, 0, 0);
                acc[1][nj] = __builtin_amdgcn_mfma_f32_16x16x32_bf16(a1, b, acc[1][nj], 0, 0, 0);
            }
        }
    }
    __syncthreads();

    #pragma unroll
    for (int j = 0; j < 8; ++j) {
        const int r = rg + 16 * j;
        const float4 f = *(const float4*)&xbt[(size_t)(m0 + r) * C_ + 4 * c4];
        bf16x4 h = { (__bf16)(c1 * f.x), (__bf16)(c1 * f.y), (__bf16)(c1 * f.z), (__bf16)(c1 * f.w) };
        *(bf16x4*)&E[r * LDE + 64 + 4 * c4] = h;
    }
    #pragma unroll
    for (int mi = 0; mi < 2; ++mi)
        #pragma unroll
        for (int nj = 0; nj < 4; ++nj)
            #pragma unroll
            for (int q = 0; q < 4; ++q) {
                const int row = w * 32 + mi * 16 + lk * 4 + q;
                const int col = nj * 16 + lr;
                E[row * LDE + col] = (__bf16)(c2 * acc[mi][nj][q]);
            }
    __syncthreads();

    f32x4 oacc[2][4] = {};
    #pragma unroll
    for (int ks = 0; ks < 4; ++ks) {
        bf16x8 a0 = *(const bf16x8*)&E[(w * 32 +  0 + lr) * LDE + ks * 32 + lk * 8];
        bf16x8 a1 = *(const bf16x8*)&E[(w * 32 + 16 + lr) * LDE + ks * 32 + lk * 8];
        #pragma unroll
        for (int nj = 0; nj < 4; ++nj) {
            bf16x8 bw = *(const bf16x8*)&Wt[(nj * 16 + lr) * LDE + ks * 32 + lk * 8];
            oacc[0][nj] = __builtin_amdgcn_mfma_f32_16x16x32_bf16(a0, bw, oacc[0][nj], 0, 0, 0);
            oacc[1][nj] = __builtin_amdgcn_mfma_f32_16x16x32_bf16(a1, bw, oacc[1][nj], 0, 0, 0);
        }
    }
    float* obt = out + (size_t)bt * N_ * C_;
    #pragma unroll
    for (int nj = 0; nj < 4; ++nj) {
        const float bv = bias[nj * 16 + lr];
        #pragma unroll
        for (int mi = 0; mi < 2; ++mi)
            #pragma unroll
            for (int q = 0; q < 4; ++q) {
                const int row = w * 32 + mi * 16 + lk * 4 + q;
                obt[(size_t)(m0 + row) * C_ + nj * 16 + lr] = oacc[mi][nj][q] + bv;
            }
    }
}

extern "C" void kernel_launch(void* const* d_in, const int* in_sizes, int n_in,
                              void* d_out, int out_size, void* d_ws, size_t ws_size,
                              hipStream_t stream) {
    const float* x       = (const float*)d_in[0];
    const float* adj     = (const float*)d_in[1];
    const float* st_emb  = (const float*)d_in[2];
    const float* weights = (const float*)d_in[3];
    const float* bias    = (const float*)d_in[4];
    const float* W1      = (const float*)d_in[5];
    const float* b1      = (const float*)d_in[6];
    const float* W2      = (const float*)d_in[7];
    const float* b2      = (const float*)d_in[8];
    float* out = (float*)d_out;
    char* ws = (char*)d_ws;
    float* cbuf = (float*)(ws + WS_CBUF);

    if (ws_size >= WS_NEED) {
        __bf16* WtB  = (__bf16*)(ws + WS_WTB);
        __bf16* adjb = (__bf16*)(ws + WS_ADJB);
        __bf16* xT   = (__bf16*)(ws + WS_XT);
        lamw_kernel<<<1, 512, 0, stream>>>(st_emb, W1, b1, W2, b2, weights, cbuf, WtB);
        cvt_adj<<<N_ * N_ / (256 * 8), 256, 0, stream>>>(adj, adjb);
        cvt_x<<<dim3(N_ / 64, B_ * T_), 256, 0, stream>>>(x, xT);
        dgcn_main2<<<dim3(N_ / BM, B_ * T_ / 2), 256, 0, stream>>>(adjb, xT, x, WtB, bias, cbuf, out);
    } else {
        lam_kernel<<<1, 384, 0, stream>>>(st_emb, W1, b1, W2, b2, cbuf);
        dgcn_fb<<<dim3(N_ / BM, B_ * T_), 256, 0, stream>>>(x, adj, weights, bias, cbuf, out);
    }
}